// Round 1
// baseline (855.689 us; speedup 1.0000x reference)
//
#include <hip/hip_runtime.h>
#include <hip/hip_bf16.h>
#include <math.h>

// Problem constants (fixed by setup_inputs)
#define BATCH 4
#define TLEN  4096
#define DDIM  1024
#define KDIM  64        // K (complex channels)
#define BT    16384     // BATCH*TLEN
#define MDIM  4096      // 4*D

typedef __attribute__((ext_vector_type(8))) __bf16 bf16x8;
typedef __attribute__((ext_vector_type(4))) float  f32x4;

#define AS1 __attribute__((address_space(1)))
#define AS3 __attribute__((address_space(3)))

__device__ __forceinline__ short f2bf(float f) {
    union { float f; unsigned int i; } u; u.f = f;
    unsigned int r = u.i + 0x7FFF + ((u.i >> 16) & 1);  // round-to-nearest-even
    return (short)(r >> 16);
}

// ---------------------------------------------------------------- converts
__global__ void cvt_bf16_kernel(const float* __restrict__ in, short* __restrict__ out, int n4) {
    int i = blockIdx.x * blockDim.x + threadIdx.x;
    int stride = gridDim.x * blockDim.x;
    for (; i < n4; i += stride) {
        float4 v = ((const float4*)in)[i];
        short4 o = make_short4(f2bf(v.x), f2bf(v.y), f2bf(v.z), f2bf(v.w));
        ((short4*)out)[i] = o;
    }
}

// ---------------------------------------------------------------- layernorm -> bf16
__global__ __launch_bounds__(256) void ln_kernel(const float* __restrict__ x,
                                                 const float* __restrict__ g,
                                                 const float* __restrict__ b,
                                                 short* __restrict__ out) {
    __shared__ float red[8];
    __shared__ float mv[2];
    int row = blockIdx.x, tid = threadIdx.x;
    const float* xr = x + (size_t)row * DDIM;
    float4 v = *(const float4*)&xr[tid * 4];
    float s  = v.x + v.y + v.z + v.w;
    float s2 = v.x*v.x + v.y*v.y + v.z*v.z + v.w*v.w;
    for (int o = 32; o; o >>= 1) { s += __shfl_down(s, o); s2 += __shfl_down(s2, o); }
    int wave = tid >> 6, lane = tid & 63;
    if (lane == 0) { red[wave] = s; red[4 + wave] = s2; }
    __syncthreads();
    if (tid == 0) {
        float ts  = red[0] + red[1] + red[2] + red[3];
        float ts2 = red[4] + red[5] + red[6] + red[7];
        float m = ts * (1.f / DDIM);
        float var = ts2 * (1.f / DDIM) - m * m;
        mv[0] = m; mv[1] = rsqrtf(var + 1e-5f);
    }
    __syncthreads();
    float m = mv[0], r = mv[1];
    const float* vv = (const float*)&v;
    short o4[4];
    #pragma unroll
    for (int j = 0; j < 4; ++j) {
        int c = tid * 4 + j;
        o4[j] = f2bf((vv[j] - m) * r * g[c] + b[c]);
    }
    *(short4*)&out[(size_t)row * DDIM + tid * 4] = make_short4(o4[0], o4[1], o4[2], o4[3]);
}

// ---------------------------------------------------------------- eig: 64-tap causal complex conv + coupling
// c[b,t,k] = sum_{s=0}^{63} lambda_k^s * beta[b,t-s,k],  lambda = sigmoid(log_decay)*e^{i*freq}
// then per-head 16x16 coupling on real and imag, output eig = [cr_c | ci_c] (f32 to d_out, bf16 to ws)
#define EIG_TT 16
#define WIN 64
__global__ __launch_bounds__(256) void eig_kernel(const float* __restrict__ beta,
                                                  const float* __restrict__ log_decay,
                                                  const float* __restrict__ freq,
                                                  const float* __restrict__ coupling,
                                                  float* __restrict__ eig_f32,
                                                  short* __restrict__ eig_bf) {
    __shared__ float bsm[EIG_TT + WIN][128];
    __shared__ float csm[EIG_TT][128];
    __shared__ float psm[4][16][16];
    int tpb = TLEN / EIG_TT;              // t-blocks per batch
    int b   = blockIdx.x / tpb;
    int t0  = (blockIdx.x % tpb) * EIG_TT;
    int tid = threadIdx.x;

    // load beta rows t0-WIN .. t0+EIG_TT-1 (zeros before sequence start)
    for (int idx = tid; idx < (EIG_TT + WIN) * 32; idx += 256) {
        int r = idx >> 5, c4 = idx & 31;
        int t = t0 - WIN + r;
        float4 val = make_float4(0.f, 0.f, 0.f, 0.f);
        if (t >= 0) val = *(const float4*)&beta[((size_t)(b * TLEN + t)) * 128 + c4 * 4];
        *(float4*)&bsm[r][c4 * 4] = val;
    }
    for (int i = tid; i < 1024; i += 256) ((float*)psm)[i] = coupling[i];
    __syncthreads();

    int k = tid & 63;
    float mag = 1.f / (1.f + __expf(-log_decay[k]));
    float th  = freq[k];
    float lr = mag * cosf(th), li = mag * sinf(th);
    #pragma unroll
    for (int p = 0; p < 4; ++p) {
        int tl = (tid >> 6) + p * 4;
        float ar = 0.f, ai = 0.f;
        for (int s = WIN - 1; s >= 0; --s) {
            float br_ = bsm[tl + WIN - s][k];
            float bi_ = bsm[tl + WIN - s][64 + k];
            float nr = lr * ar - li * ai + br_;
            float ni = lr * ai + li * ar + bi_;
            ar = nr; ai = ni;
        }
        csm[tl][k] = ar; csm[tl][64 + k] = ai;
    }
    __syncthreads();

    #pragma unroll
    for (int p = 0; p < 8; ++p) {
        int idx = tid + p * 256;          // 0..2047
        int c = idx & 127, tl = idx >> 7;
        int im = c >> 6, hj = c & 63, h = hj >> 4, j = hj & 15;
        float acc = 0.f;
        #pragma unroll
        for (int kk = 0; kk < 16; ++kk) acc += psm[h][j][kk] * csm[tl][im * 64 + h * 16 + kk];
        size_t o = ((size_t)(b * TLEN + t0 + tl)) * 128 + c;
        eig_f32[o] = acc;
        eig_bf[o]  = f2bf(acc);
    }
}

// ---------------------------------------------------------------- bf16 MFMA GEMM, C = A(M,K) * Bt(N,K)^T
// m97 structure: 128x128 tile, BK=32, 4 waves each computing 64x64, global_load_lds width 16.
enum { E_NONE = 0, E_SIG = 1, E_SILU_BF = 2, E_RES = 3 };

template <int EPI>
__global__ __launch_bounds__(256) void gemm_bt(const short* __restrict__ A,
                                               const short* __restrict__ Bt,
                                               void* __restrict__ C,
                                               int Ndim, int Kdim,
                                               const float* __restrict__ bias,
                                               const float* __restrict__ res) {
    __shared__ short Asm[128 * 32];
    __shared__ short Bsm[128 * 32];
    int nb = Ndim >> 7;
    int bm = blockIdx.x / nb, bn = blockIdx.x % nb;
    int m0 = bm << 7, n0 = bn << 7;
    int tid = threadIdx.x, lane = tid & 63, wave = tid >> 6;
    int wr = wave >> 1, wc = wave & 1;
    f32x4 acc[4][4] = {};

    int ldrow = lane >> 2;             // row within 16-row chunk
    int ldcol = (lane & 3) * 8;        // element (short) offset in K within tile
    int frow = lane & 15, fch = lane >> 4;

    for (int k0 = 0; k0 < Kdim; k0 += 32) {
        #pragma unroll
        for (int r = 0; r < 2; ++r) {
            int chunk = wave * 2 + r;                  // 0..7, 16 rows each
            int row = chunk * 16 + ldrow;
            __builtin_amdgcn_global_load_lds(
                (const AS1 unsigned int*)(A + (size_t)(m0 + row) * Kdim + k0 + ldcol),
                (AS3 unsigned int*)(Asm + chunk * 512 + lane * 8), 16, 0, 0);
            __builtin_amdgcn_global_load_lds(
                (const AS1 unsigned int*)(Bt + (size_t)(n0 + row) * Kdim + k0 + ldcol),
                (AS3 unsigned int*)(Bsm + chunk * 512 + lane * 8), 16, 0, 0);
        }
        __syncthreads();
        bf16x8 af[4], bf[4];
        #pragma unroll
        for (int m = 0; m < 4; ++m) af[m] = *(const bf16x8*)&Asm[(wr * 64 + m * 16 + frow) * 32 + fch * 8];
        #pragma unroll
        for (int n = 0; n < 4; ++n) bf[n] = *(const bf16x8*)&Bsm[(wc * 64 + n * 16 + frow) * 32 + fch * 8];
        #pragma unroll
        for (int m = 0; m < 4; ++m)
            #pragma unroll
            for (int n = 0; n < 4; ++n)
                acc[m][n] = __builtin_amdgcn_mfma_f32_16x16x32_bf16(af[m], bf[n], acc[m][n], 0, 0, 0);
        __syncthreads();
    }

    // epilogue: C row = (lane>>4)*4 + j, col = lane&15 within each 16x16 fragment
    #pragma unroll
    for (int m = 0; m < 4; ++m) {
        int row = m0 + wr * 64 + m * 16 + fch * 4;
        #pragma unroll
        for (int n = 0; n < 4; ++n) {
            int col = n0 + wc * 64 + n * 16 + frow;
            #pragma unroll
            for (int j = 0; j < 4; ++j) {
                float v = acc[m][n][j];
                size_t o = (size_t)(row + j) * Ndim + col;
                if (EPI == E_NONE) {
                    ((float*)C)[o] = v;
                } else if (EPI == E_SIG) {
                    float t = v + bias[col];
                    ((float*)C)[o] = 1.f / (1.f + __expf(-t));
                } else if (EPI == E_SILU_BF) {
                    float t = v + bias[col];
                    ((short*)C)[o] = f2bf(t / (1.f + __expf(-t)));
                } else {  // E_RES
                    ((float*)C)[o] = v + bias[col] + res[o];
                }
            }
        }
    }
}

// ---------------------------------------------------------------- fuse: x1 = x + sigmoid_gate * out
__global__ void fuse_gate_kernel(const float4* __restrict__ x, const float4* __restrict__ gs,
                                 const float4* __restrict__ op, float4* __restrict__ x1, int n4) {
    int i = blockIdx.x * blockDim.x + threadIdx.x;
    int stride = gridDim.x * blockDim.x;
    for (; i < n4; i += stride) {
        float4 a = x[i], s = gs[i], o = op[i];
        x1[i] = make_float4(a.x + s.x * o.x, a.y + s.y * o.y, a.z + s.z * o.z, a.w + s.w * o.w);
    }
}

// ---------------------------------------------------------------- launch
extern "C" void kernel_launch(void* const* d_in, const int* in_sizes, int n_in,
                              void* d_out, int out_size, void* d_ws, size_t ws_size,
                              hipStream_t stream) {
    const float* x          = (const float*)d_in[0];
    const float* in_proj_w  = (const float*)d_in[1];
    const float* log_decay  = (const float*)d_in[2];
    const float* frequency  = (const float*)d_in[3];
    const float* coupling   = (const float*)d_in[4];
    const float* out_proj_w = (const float*)d_in[5];
    const float* gate_w     = (const float*)d_in[6];
    const float* gate_b     = (const float*)d_in[7];
    const float* n1_g       = (const float*)d_in[8];
    const float* n1_b       = (const float*)d_in[9];
    const float* n2_g       = (const float*)d_in[10];
    const float* n2_b       = (const float*)d_in[11];
    const float* mlp_w1     = (const float*)d_in[12];
    const float* mlp_b1     = (const float*)d_in[13];
    const float* mlp_w2     = (const float*)d_in[14];
    const float* mlp_b2     = (const float*)d_in[15];

    float* out_x   = (float*)d_out;                 // (BT, D) final
    float* out_eig = out_x + (size_t)BT * DDIM;     // (BT, 128)

    char* ws = (char*)d_ws;
    short* w_inproj  = (short*)(ws + 0);            //  262144 B
    short* w_outproj = (short*)(ws + 262144);       //  262144 B
    short* w_gate    = (short*)(ws + 524288);       // 2097152 B
    short* w_1       = (short*)(ws + 2621440);      // 8388608 B
    short* w_2       = (short*)(ws + 11010048);     // 8388608 B
    short* xn        = (short*)(ws + 19398656);     // 33554432 B (reused for x2n)
    float* beta      = (float*)(ws + 52953088);     // 8388608 B
    short* eig_bf    = (short*)(ws + 61341696);     // 4194304 B
    float* gsig      = (float*)(ws + 65536000);     // 67108864 B
    float* outp      = (float*)(ws + 132644864);    // 67108864 B  (end: 199753728)
    short* hid       = (short*)(ws + 65536000);     // 134217728 B, reuses gsig+outp after fuse

    // weight conversions (f32 -> bf16), every call (ws is re-poisoned)
    cvt_bf16_kernel<<<64,   256, 0, stream>>>(in_proj_w,  w_inproj,  131072 / 4);
    cvt_bf16_kernel<<<64,   256, 0, stream>>>(out_proj_w, w_outproj, 131072 / 4);
    cvt_bf16_kernel<<<256,  256, 0, stream>>>(gate_w,     w_gate,    1048576 / 4);
    cvt_bf16_kernel<<<1024, 256, 0, stream>>>(mlp_w1,     w_1,       4194304 / 4);
    cvt_bf16_kernel<<<1024, 256, 0, stream>>>(mlp_w2,     w_2,       4194304 / 4);

    // xn = LN1(x) in bf16
    ln_kernel<<<BT, 256, 0, stream>>>(x, n1_g, n1_b, xn);

    // beta = xn @ in_proj_w^T   (M=BT, N=128, K=1024)
    gemm_bt<E_NONE><<<(BT / 128) * (128 / 128), 256, 0, stream>>>(xn, w_inproj, beta, 128, 1024, nullptr, nullptr);

    // eig (conv + coupling) -> out_eig (f32) + eig_bf (bf16)
    eig_kernel<<<BATCH * (TLEN / EIG_TT), 256, 0, stream>>>(beta, log_decay, frequency, coupling, out_eig, eig_bf);

    // out = eig @ out_proj_w^T  (N=1024, K=128)
    gemm_bt<E_NONE><<<(BT / 128) * (1024 / 128), 256, 0, stream>>>(eig_bf, w_outproj, outp, 1024, 128, nullptr, nullptr);

    // gsig = sigmoid(xn @ gate_w^T + gate_b)  (N=1024, K=1024)
    gemm_bt<E_SIG><<<(BT / 128) * (1024 / 128), 256, 0, stream>>>(xn, w_gate, gsig, 1024, 1024, gate_b, nullptr);

    // x1 = x + gsig * outp  -> d_out (x region)
    fuse_gate_kernel<<<2048, 256, 0, stream>>>((const float4*)x, (const float4*)gsig,
                                               (const float4*)outp, (float4*)out_x, BT * DDIM / 4);

    // x2n = LN2(x1) in bf16 (reuse xn buffer)
    ln_kernel<<<BT, 256, 0, stream>>>(out_x, n2_g, n2_b, xn);

    // hid = silu(x2n @ mlp_w1^T + b1) in bf16  (N=4096, K=1024)
    gemm_bt<E_SILU_BF><<<(BT / 128) * (4096 / 128), 256, 0, stream>>>(xn, w_1, hid, 4096, 1024, mlp_b1, nullptr);

    // x_final = x1 + hid @ mlp_w2^T + b2  (N=1024, K=4096), in-place on d_out
    gemm_bt<E_RES><<<(BT / 128) * (1024 / 128), 256, 0, stream>>>(hid, w_2, out_x, 1024, 4096, mlp_b2, out_x);
}

// Round 3
// 636.112 us; speedup vs baseline: 1.3452x; 1.3452x over previous
//
#include <hip/hip_runtime.h>
#include <hip/hip_bf16.h>
#include <math.h>

// Problem constants (fixed by setup_inputs)
#define BATCH 4
#define TLEN  4096
#define DDIM  1024
#define BT    16384     // BATCH*TLEN

typedef __attribute__((ext_vector_type(8))) __bf16 bf16x8;
typedef __attribute__((ext_vector_type(4))) float  f32x4;

#define AS1 __attribute__((address_space(1)))
#define AS3 __attribute__((address_space(3)))

__device__ __forceinline__ short f2bf(float f) {
    union { float f; unsigned int i; } u; u.f = f;
    unsigned int r = u.i + 0x7FFF + ((u.i >> 16) & 1);  // round-to-nearest-even
    return (short)(r >> 16);
}

// ---------------------------------------------------------------- converts
__global__ void cvt_bf16_kernel(const float* __restrict__ in, short* __restrict__ out, int n4) {
    int i = blockIdx.x * blockDim.x + threadIdx.x;
    int stride = gridDim.x * blockDim.x;
    for (; i < n4; i += stride) {
        float4 v = ((const float4*)in)[i];
        short4 o = make_short4(f2bf(v.x), f2bf(v.y), f2bf(v.z), f2bf(v.w));
        ((short4*)out)[i] = o;
    }
}

// ---------------------------------------------------------------- layernorm -> bf16
__global__ __launch_bounds__(256) void ln_kernel(const float* __restrict__ x,
                                                 const float* __restrict__ g,
                                                 const float* __restrict__ b,
                                                 short* __restrict__ out) {
    __shared__ float red[8];
    __shared__ float mv[2];
    int row = blockIdx.x, tid = threadIdx.x;
    const float* xr = x + (size_t)row * DDIM;
    float4 v = *(const float4*)&xr[tid * 4];
    float s  = v.x + v.y + v.z + v.w;
    float s2 = v.x*v.x + v.y*v.y + v.z*v.z + v.w*v.w;
    for (int o = 32; o; o >>= 1) { s += __shfl_down(s, o); s2 += __shfl_down(s2, o); }
    int wave = tid >> 6, lane = tid & 63;
    if (lane == 0) { red[wave] = s; red[4 + wave] = s2; }
    __syncthreads();
    if (tid == 0) {
        float ts  = red[0] + red[1] + red[2] + red[3];
        float ts2 = red[4] + red[5] + red[6] + red[7];
        float m = ts * (1.f / DDIM);
        float var = ts2 * (1.f / DDIM) - m * m;
        mv[0] = m; mv[1] = rsqrtf(var + 1e-5f);
    }
    __syncthreads();
    float m = mv[0], r = mv[1];
    const float* vv = (const float*)&v;
    short o4[4];
    #pragma unroll
    for (int j = 0; j < 4; ++j) {
        int c = tid * 4 + j;
        o4[j] = f2bf((vv[j] - m) * r * g[c] + b[c]);
    }
    *(short4*)&out[(size_t)row * DDIM + tid * 4] = make_short4(o4[0], o4[1], o4[2], o4[3]);
}

// ---------------------------------------------------------------- eig: 64-tap causal complex conv + coupling
#define EIG_TT 16
#define WIN 64
__global__ __launch_bounds__(256) void eig_kernel(const float* __restrict__ beta,
                                                  const float* __restrict__ log_decay,
                                                  const float* __restrict__ freq,
                                                  const float* __restrict__ coupling,
                                                  float* __restrict__ eig_f32,
                                                  short* __restrict__ eig_bf) {
    __shared__ float bsm[EIG_TT + WIN][128];
    __shared__ float csm[EIG_TT][128];
    __shared__ float psm[4][16][16];
    int tpb = TLEN / EIG_TT;
    int b   = blockIdx.x / tpb;
    int t0  = (blockIdx.x % tpb) * EIG_TT;
    int tid = threadIdx.x;

    for (int idx = tid; idx < (EIG_TT + WIN) * 32; idx += 256) {
        int r = idx >> 5, c4 = idx & 31;
        int t = t0 - WIN + r;
        float4 val = make_float4(0.f, 0.f, 0.f, 0.f);
        if (t >= 0) val = *(const float4*)&beta[((size_t)(b * TLEN + t)) * 128 + c4 * 4];
        *(float4*)&bsm[r][c4 * 4] = val;
    }
    for (int i = tid; i < 1024; i += 256) ((float*)psm)[i] = coupling[i];
    __syncthreads();

    int k = tid & 63;
    float mag = 1.f / (1.f + __expf(-log_decay[k]));
    float th  = freq[k];
    float lr = mag * cosf(th), li = mag * sinf(th);
    #pragma unroll
    for (int p = 0; p < 4; ++p) {
        int tl = (tid >> 6) + p * 4;
        float ar = 0.f, ai = 0.f;
        for (int s = WIN - 1; s >= 0; --s) {
            float br_ = bsm[tl + WIN - s][k];
            float bi_ = bsm[tl + WIN - s][64 + k];
            float nr = lr * ar - li * ai + br_;
            float ni = lr * ai + li * ar + bi_;
            ar = nr; ai = ni;
        }
        csm[tl][k] = ar; csm[tl][64 + k] = ai;
    }
    __syncthreads();

    #pragma unroll
    for (int p = 0; p < 8; ++p) {
        int idx = tid + p * 256;
        int c = idx & 127, tl = idx >> 7;
        int im = c >> 6, hj = c & 63, h = hj >> 4, j = hj & 15;
        float acc = 0.f;
        #pragma unroll
        for (int kk = 0; kk < 16; ++kk) acc += psm[h][j][kk] * csm[tl][im * 64 + h * 16 + kk];
        size_t o = ((size_t)(b * TLEN + t0 + tl)) * 128 + c;
        eig_f32[o] = acc;
        eig_bf[o]  = f2bf(acc);
    }
}

// ---------------------------------------------------------------- small 128x128 GEMM (beta only, N=128)
__global__ __launch_bounds__(256) void gemm_bt(const short* __restrict__ A,
                                               const short* __restrict__ Bt,
                                               float* __restrict__ C,
                                               int Ndim, int Kdim) {
    __shared__ short Asm[128 * 32];
    __shared__ short Bsm[128 * 32];
    int nb = Ndim >> 7;
    int bm = blockIdx.x / nb, bn = blockIdx.x % nb;
    int m0 = bm << 7, n0 = bn << 7;
    int tid = threadIdx.x, lane = tid & 63, wave = tid >> 6;
    int wr = wave >> 1, wc = wave & 1;
    f32x4 acc[4][4] = {};
    int ldrow = lane >> 2;
    int ldcol = (lane & 3) * 8;
    int frow = lane & 15, fch = lane >> 4;

    for (int k0 = 0; k0 < Kdim; k0 += 32) {
        #pragma unroll
        for (int r = 0; r < 2; ++r) {
            int chunk = wave * 2 + r;
            int row = chunk * 16 + ldrow;
            __builtin_amdgcn_global_load_lds(
                (const AS1 unsigned int*)(A + (size_t)(m0 + row) * Kdim + k0 + ldcol),
                (AS3 unsigned int*)(Asm + chunk * 512 + lane * 8), 16, 0, 0);
            __builtin_amdgcn_global_load_lds(
                (const AS1 unsigned int*)(Bt + (size_t)(n0 + row) * Kdim + k0 + ldcol),
                (AS3 unsigned int*)(Bsm + chunk * 512 + lane * 8), 16, 0, 0);
        }
        __syncthreads();
        bf16x8 af[4], bf[4];
        #pragma unroll
        for (int m = 0; m < 4; ++m) af[m] = *(const bf16x8*)&Asm[(wr * 64 + m * 16 + frow) * 32 + fch * 8];
        #pragma unroll
        for (int n = 0; n < 4; ++n) bf[n] = *(const bf16x8*)&Bsm[(wc * 64 + n * 16 + frow) * 32 + fch * 8];
        #pragma unroll
        for (int m = 0; m < 4; ++m)
            #pragma unroll
            for (int n = 0; n < 4; ++n)
                acc[m][n] = __builtin_amdgcn_mfma_f32_16x16x32_bf16(af[m], bf[n], acc[m][n], 0, 0, 0);
        __syncthreads();
    }
    #pragma unroll
    for (int m = 0; m < 4; ++m) {
        int row = m0 + wr * 64 + m * 16 + fch * 4;
        #pragma unroll
        for (int n = 0; n < 4; ++n) {
            int col = n0 + wc * 64 + n * 16 + frow;
            #pragma unroll
            for (int j = 0; j < 4; ++j)
                C[(size_t)(row + j) * Ndim + col] = acc[m][n][j];
        }
    }
}

// ---------------------------------------------------------------- 256x256 8-phase GEMM (T1+T2+T3+T4+T5)
// C(M,N) = A(M,K) * Bt(N,K)^T. 512 thr = 8 waves (2Mx4N), BK=64, LDS 128 KiB dbuf.
// Per K-tile: 4 half-tiles (A0,A1,B0,B1 of 128x64). Swizzle: 16B slot ^= (row&7),
// applied on global SOURCE (stage) and on ds_read addr; LDS dest stays linear.
enum { E_NONE = 0, E_GATEFUSE = 1, E_SILU_BF = 2, E_RES = 3 };

#define MEMFENCE asm volatile("" ::: "memory")
#define BARRIER do { MEMFENCE; __builtin_amdgcn_sched_barrier(0); \
                     __builtin_amdgcn_s_barrier(); } while (0)

// stage one 128x64 half-tile (16 KiB): 2 x global_load_lds(16B) per thread
#define STAGE(src, grow0, tau_, ldsShortBase) do { \
    int _i = tid; \
    _Pragma("unroll") \
    for (int _r = 0; _r < 2; ++_r, _i += 512) { \
        int _row = _i >> 3, _slot = _i & 7; \
        const short* _gp = (src) + (size_t)((grow0) + _row) * Kdim + ((tau_) << 6) \
                           + ((_slot ^ (_row & 7)) << 3); \
        __builtin_amdgcn_global_load_lds((const AS1 unsigned int*)_gp, \
            (AS3 unsigned int*)(lds + (ldsShortBase) + _i * 8), 16, 0, 0); \
    } \
} while (0)

#define LOAD_A(mq) do { \
    af0 = *(const bf16x8*)(Ab + (2*(mq))  *2048 + lrb + x0); \
    af1 = *(const bf16x8*)(Ab + (2*(mq))  *2048 + lrb + x1); \
    af2 = *(const bf16x8*)(Ab + (2*(mq)+1)*2048 + lrb + x0); \
    af3 = *(const bf16x8*)(Ab + (2*(mq)+1)*2048 + lrb + x1); \
} while (0)

#define PHASE_MFMA(mA, mB) do { \
    _Pragma("unroll") \
    for (int n = 0; n < 4; ++n) { \
        acc[mA][n] = __builtin_amdgcn_mfma_f32_16x16x32_bf16(af0, bfrag[n][0], acc[mA][n], 0, 0, 0); \
        acc[mA][n] = __builtin_amdgcn_mfma_f32_16x16x32_bf16(af1, bfrag[n][1], acc[mA][n], 0, 0, 0); \
        acc[mB][n] = __builtin_amdgcn_mfma_f32_16x16x32_bf16(af2, bfrag[n][0], acc[mB][n], 0, 0, 0); \
        acc[mB][n] = __builtin_amdgcn_mfma_f32_16x16x32_bf16(af3, bfrag[n][1], acc[mB][n], 0, 0, 0); \
    } \
} while (0)

template <int EPI>
__global__ __launch_bounds__(512, 2) void gemm256(const short* __restrict__ A,
                                                  const short* __restrict__ Bt,
                                                  void* __restrict__ C,
                                                  int Ndim, int Kdim,
                                                  const float* __restrict__ bias,
                                                  const float* __restrict__ res,
                                                  const float* __restrict__ xin,
                                                  const float* __restrict__ outp) {
    __shared__ short lds[65536];                 // 128 KiB: 2 buf x (A 2x8192 | B 2x8192)
    const int NT = Kdim >> 6;
    const int nb = Ndim >> 8;
    int nwg = gridDim.x;
    int wg  = blockIdx.x;
    int swz = (wg & 7) * (nwg >> 3) + (wg >> 3);     // bijective: nwg % 8 == 0
    int bm = swz / nb, bn = swz % nb;
    int m0 = bm << 8, n0 = bn << 8;
    int tid = threadIdx.x, lane = tid & 63, wave = tid >> 6;
    int wr = wave >> 2, wc = wave & 3;
    int frow = lane & 15, fch = lane >> 4;

    f32x4 acc[8][4] = {};
    bf16x8 bfrag[4][2];

    // lane-constant read offsets (bytes within one 128x64 half; 16B-slot swizzle)
    int lrb = frow * 128;
    int sx  = frow & 7;
    int x0  = (fch ^ sx) << 4;
    int x1  = ((fch + 4) ^ sx) << 4;

    // prologue: tile0 (4 halves -> buf0) + B0,B1,A0 of tile1 -> buf1
    STAGE(Bt, n0,       0, 16384);
    STAGE(Bt, n0 + 128, 0, 16384 + 8192);
    STAGE(A,  m0,       0, 0);
    STAGE(A,  m0 + 128, 0, 8192);
    if (NT > 1) {
        STAGE(Bt, n0,       1, 32768 + 16384);
        STAGE(Bt, n0 + 128, 1, 32768 + 16384 + 8192);
        STAGE(A,  m0,       1, 32768);
    }
    asm volatile("s_waitcnt vmcnt(6)" ::: "memory");
    __builtin_amdgcn_sched_barrier(0);
    __builtin_amdgcn_s_barrier();

    for (int tau = 0; tau < NT; ++tau) {
        const int p = tau & 1, pn = p ^ 1;
        const char* LB = (const char*)lds + p * 65536;
        const char* Ab = LB + wr * 16384;
        const char* Bb = LB + 32768 + (wc >> 1) * 16384 + (wc & 1) * 8192;
        const int pB = p  * 32768;
        const int pN = pn * 32768;
        bf16x8 af0, af1, af2, af3;

        // ---- phase 1: A m=0,1 + all B frags; stage A1(tau+1) ----
        LOAD_A(0);
        #pragma unroll
        for (int n = 0; n < 4; ++n) {
            bfrag[n][0] = *(const bf16x8*)(Bb + n * 2048 + lrb + x0);
            bfrag[n][1] = *(const bf16x8*)(Bb + n * 2048 + lrb + x1);
        }
        if (tau + 1 < NT) STAGE(A, m0 + 128, tau + 1, pN + 8192);
        BARRIER;
        __builtin_amdgcn_s_setprio(1);
        PHASE_MFMA(0, 1);
        __builtin_amdgcn_s_setprio(0);
        BARRIER;

        // ---- phase 2: A m=2,3; stage B0(tau+2) ----
        LOAD_A(1);
        if (tau + 2 < NT) STAGE(Bt, n0, tau + 2, pB + 16384);
        BARRIER;
        __builtin_amdgcn_s_setprio(1);
        PHASE_MFMA(2, 3);
        __builtin_amdgcn_s_setprio(0);
        BARRIER;

        // ---- phase 3: A m=4,5; stage B1(tau+2) ----
        LOAD_A(2);
        if (tau + 2 < NT) STAGE(Bt, n0 + 128, tau + 2, pB + 16384 + 8192);
        BARRIER;
        __builtin_amdgcn_s_setprio(1);
        PHASE_MFMA(4, 5);
        __builtin_amdgcn_s_setprio(0);
        BARRIER;

        // ---- phase 4: A m=6,7; stage A0(tau+2) after MFMA; counted vmcnt ----
        LOAD_A(3);
        BARRIER;
        __builtin_amdgcn_s_setprio(1);
        PHASE_MFMA(6, 7);
        __builtin_amdgcn_s_setprio(0);
        if (tau + 2 < NT) {
            STAGE(A, m0, tau + 2, pB);
            asm volatile("s_waitcnt vmcnt(6)" ::: "memory");
        } else {
            asm volatile("s_waitcnt vmcnt(0)" ::: "memory");
        }
        BARRIER;
    }

    // epilogue
    #pragma unroll
    for (int m = 0; m < 8; ++m) {
        int row = m0 + wr * 128 + m * 16 + fch * 4;
        #pragma unroll
        for (int n = 0; n < 4; ++n) {
            int col = n0 + wc * 64 + n * 16 + frow;
            #pragma unroll
            for (int j = 0; j < 4; ++j) {
                float v = acc[m][n][j];
                size_t o = (size_t)(row + j) * Ndim + col;
                if (EPI == E_NONE) {
                    ((float*)C)[o] = v;
                } else if (EPI == E_GATEFUSE) {
                    float t = v + bias[col];
                    float s = 1.f / (1.f + __expf(-t));
                    ((float*)C)[o] = xin[o] + s * outp[o];
                } else if (EPI == E_SILU_BF) {
                    float t = v + bias[col];
                    ((short*)C)[o] = f2bf(t / (1.f + __expf(-t)));
                } else {  // E_RES
                    ((float*)C)[o] = v + bias[col] + res[o];
                }
            }
        }
    }
}

// ---------------------------------------------------------------- launch
extern "C" void kernel_launch(void* const* d_in, const int* in_sizes, int n_in,
                              void* d_out, int out_size, void* d_ws, size_t ws_size,
                              hipStream_t stream) {
    const float* x          = (const float*)d_in[0];
    const float* in_proj_w  = (const float*)d_in[1];
    const float* log_decay  = (const float*)d_in[2];
    const float* frequency  = (const float*)d_in[3];
    const float* coupling   = (const float*)d_in[4];
    const float* out_proj_w = (const float*)d_in[5];
    const float* gate_w     = (const float*)d_in[6];
    const float* gate_b     = (const float*)d_in[7];
    const float* n1_g       = (const float*)d_in[8];
    const float* n1_b       = (const float*)d_in[9];
    const float* n2_g       = (const float*)d_in[10];
    const float* n2_b       = (const float*)d_in[11];
    const float* mlp_w1     = (const float*)d_in[12];
    const float* mlp_b1     = (const float*)d_in[13];
    const float* mlp_w2     = (const float*)d_in[14];
    const float* mlp_b2     = (const float*)d_in[15];

    float* out_x   = (float*)d_out;
    float* out_eig = out_x + (size_t)BT * DDIM;

    char* ws = (char*)d_ws;
    short* w_inproj  = (short*)(ws + 0);
    short* w_outproj = (short*)(ws + 262144);
    short* w_gate    = (short*)(ws + 524288);
    short* w_1       = (short*)(ws + 2621440);
    short* w_2       = (short*)(ws + 11010048);
    short* xn        = (short*)(ws + 19398656);
    float* beta      = (float*)(ws + 52953088);
    short* eig_bf    = (short*)(ws + 61341696);
    short* hid       = (short*)(ws + 65536000);     // 134217728 B (after outp dead)
    float* outp      = (float*)(ws + 132644864);    // 67108864 B

    cvt_bf16_kernel<<<64,   256, 0, stream>>>(in_proj_w,  w_inproj,  131072 / 4);
    cvt_bf16_kernel<<<64,   256, 0, stream>>>(out_proj_w, w_outproj, 131072 / 4);
    cvt_bf16_kernel<<<256,  256, 0, stream>>>(gate_w,     w_gate,    1048576 / 4);
    cvt_bf16_kernel<<<1024, 256, 0, stream>>>(mlp_w1,     w_1,       4194304 / 4);
    cvt_bf16_kernel<<<1024, 256, 0, stream>>>(mlp_w2,     w_2,       4194304 / 4);

    // xn = LN1(x)
    ln_kernel<<<BT, 256, 0, stream>>>(x, n1_g, n1_b, xn);

    // beta = xn @ in_proj_w^T  (N=128, K=1024) - small kernel
    gemm_bt<<<BT / 128, 256, 0, stream>>>(xn, w_inproj, beta, 128, 1024);

    // eig conv + coupling
    eig_kernel<<<BATCH * (TLEN / EIG_TT), 256, 0, stream>>>(beta, log_decay, frequency, coupling, out_eig, eig_bf);

    // out = eig @ out_proj_w^T  (N=1024, K=128)
    gemm256<E_NONE><<<(BT / 256) * (1024 / 256), 512, 0, stream>>>(
        eig_bf, w_outproj, outp, 1024, 128, nullptr, nullptr, nullptr, nullptr);

    // x1 = x + sigmoid(xn @ gate_w^T + gate_b) * outp  -> d_out  (N=1024, K=1024)
    gemm256<E_GATEFUSE><<<(BT / 256) * (1024 / 256), 512, 0, stream>>>(
        xn, w_gate, out_x, 1024, 1024, gate_b, nullptr, x, outp);

    // x2n = LN2(x1)
    ln_kernel<<<BT, 256, 0, stream>>>(out_x, n2_g, n2_b, xn);

    // hid = silu(x2n @ mlp_w1^T + b1) bf16  (N=4096, K=1024)
    gemm256<E_SILU_BF><<<(BT / 256) * (4096 / 256), 512, 0, stream>>>(
        xn, w_1, hid, 4096, 1024, mlp_b1, nullptr, nullptr, nullptr);

    // x = x1 + hid @ mlp_w2^T + b2  (N=1024, K=4096), in-place RMW on d_out
    gemm256<E_RES><<<(BT / 256) * (1024 / 256), 512, 0, stream>>>(
        hid, w_2, out_x, 1024, 4096, mlp_b2, out_x, nullptr, nullptr);
}

// Round 4
// 629.984 us; speedup vs baseline: 1.3583x; 1.0097x over previous
//
#include <hip/hip_runtime.h>
#include <hip/hip_bf16.h>
#include <math.h>

// Problem constants (fixed by setup_inputs)
#define BATCH 4
#define TLEN  4096
#define DDIM  1024
#define BT    16384     // BATCH*TLEN

typedef __attribute__((ext_vector_type(8))) __bf16 bf16x8;
typedef __attribute__((ext_vector_type(4))) float  f32x4;

#define AS1 __attribute__((address_space(1)))
#define AS3 __attribute__((address_space(3)))

__device__ __forceinline__ short f2bf(float f) {
    union { float f; unsigned int i; } u; u.f = f;
    unsigned int r = u.i + 0x7FFF + ((u.i >> 16) & 1);  // round-to-nearest-even
    return (short)(r >> 16);
}

// ---------------------------------------------------------------- converts
__global__ void cvt_bf16_kernel(const float* __restrict__ in, short* __restrict__ out, int n4) {
    int i = blockIdx.x * blockDim.x + threadIdx.x;
    int stride = gridDim.x * blockDim.x;
    for (; i < n4; i += stride) {
        float4 v = ((const float4*)in)[i];
        short4 o = make_short4(f2bf(v.x), f2bf(v.y), f2bf(v.z), f2bf(v.w));
        ((short4*)out)[i] = o;
    }
}

// ---------------------------------------------------------------- layernorm -> bf16
__global__ __launch_bounds__(256) void ln_kernel(const float* __restrict__ x,
                                                 const float* __restrict__ g,
                                                 const float* __restrict__ b,
                                                 short* __restrict__ out) {
    __shared__ float red[8];
    __shared__ float mv[2];
    int row = blockIdx.x, tid = threadIdx.x;
    const float* xr = x + (size_t)row * DDIM;
    float4 v = *(const float4*)&xr[tid * 4];
    float s  = v.x + v.y + v.z + v.w;
    float s2 = v.x*v.x + v.y*v.y + v.z*v.z + v.w*v.w;
    for (int o = 32; o; o >>= 1) { s += __shfl_down(s, o); s2 += __shfl_down(s2, o); }
    int wave = tid >> 6, lane = tid & 63;
    if (lane == 0) { red[wave] = s; red[4 + wave] = s2; }
    __syncthreads();
    if (tid == 0) {
        float ts  = red[0] + red[1] + red[2] + red[3];
        float ts2 = red[4] + red[5] + red[6] + red[7];
        float m = ts * (1.f / DDIM);
        float var = ts2 * (1.f / DDIM) - m * m;
        mv[0] = m; mv[1] = rsqrtf(var + 1e-5f);
    }
    __syncthreads();
    float m = mv[0], r = mv[1];
    const float* vv = (const float*)&v;
    short o4[4];
    #pragma unroll
    for (int j = 0; j < 4; ++j) {
        int c = tid * 4 + j;
        o4[j] = f2bf((vv[j] - m) * r * g[c] + b[c]);
    }
    *(short4*)&out[(size_t)row * DDIM + tid * 4] = make_short4(o4[0], o4[1], o4[2], o4[3]);
}

// ---------------------------------------------------------------- eig: 64-tap causal complex conv + coupling
#define EIG_TT 16
#define WIN 64
__global__ __launch_bounds__(256) void eig_kernel(const float* __restrict__ beta,
                                                  const float* __restrict__ log_decay,
                                                  const float* __restrict__ freq,
                                                  const float* __restrict__ coupling,
                                                  float* __restrict__ eig_f32,
                                                  short* __restrict__ eig_bf) {
    __shared__ float bsm[EIG_TT + WIN][128];
    __shared__ float csm[EIG_TT][128];
    __shared__ float psm[4][16][16];
    int tpb = TLEN / EIG_TT;
    int b   = blockIdx.x / tpb;
    int t0  = (blockIdx.x % tpb) * EIG_TT;
    int tid = threadIdx.x;

    for (int idx = tid; idx < (EIG_TT + WIN) * 32; idx += 256) {
        int r = idx >> 5, c4 = idx & 31;
        int t = t0 - WIN + r;
        float4 val = make_float4(0.f, 0.f, 0.f, 0.f);
        if (t >= 0) val = *(const float4*)&beta[((size_t)(b * TLEN + t)) * 128 + c4 * 4];
        *(float4*)&bsm[r][c4 * 4] = val;
    }
    for (int i = tid; i < 1024; i += 256) ((float*)psm)[i] = coupling[i];
    __syncthreads();

    int k = tid & 63;
    float mag = 1.f / (1.f + __expf(-log_decay[k]));
    float th  = freq[k];
    float lr = mag * cosf(th), li = mag * sinf(th);
    #pragma unroll
    for (int p = 0; p < 4; ++p) {
        int tl = (tid >> 6) + p * 4;
        float ar = 0.f, ai = 0.f;
        for (int s = WIN - 1; s >= 0; --s) {
            float br_ = bsm[tl + WIN - s][k];
            float bi_ = bsm[tl + WIN - s][64 + k];
            float nr = lr * ar - li * ai + br_;
            float ni = lr * ai + li * ar + bi_;
            ar = nr; ai = ni;
        }
        csm[tl][k] = ar; csm[tl][64 + k] = ai;
    }
    __syncthreads();

    #pragma unroll
    for (int p = 0; p < 8; ++p) {
        int idx = tid + p * 256;
        int c = idx & 127, tl = idx >> 7;
        int im = c >> 6, hj = c & 63, h = hj >> 4, j = hj & 15;
        float acc = 0.f;
        #pragma unroll
        for (int kk = 0; kk < 16; ++kk) acc += psm[h][j][kk] * csm[tl][im * 64 + h * 16 + kk];
        size_t o = ((size_t)(b * TLEN + t0 + tl)) * 128 + c;
        eig_f32[o] = acc;
        eig_bf[o]  = f2bf(acc);
    }
}

// ---------------------------------------------------------------- small 128x128 GEMM (beta only, N=128)
__global__ __launch_bounds__(256) void gemm_bt(const short* __restrict__ A,
                                               const short* __restrict__ Bt,
                                               float* __restrict__ C,
                                               int Ndim, int Kdim) {
    __shared__ short Asm[128 * 32];
    __shared__ short Bsm[128 * 32];
    int nb = Ndim >> 7;
    int bm = blockIdx.x / nb, bn = blockIdx.x % nb;
    int m0 = bm << 7, n0 = bn << 7;
    int tid = threadIdx.x, lane = tid & 63, wave = tid >> 6;
    int wr = wave >> 1, wc = wave & 1;
    f32x4 acc[4][4] = {};
    int ldrow = lane >> 2;
    int ldcol = (lane & 3) * 8;
    int frow = lane & 15, fch = lane >> 4;

    for (int k0 = 0; k0 < Kdim; k0 += 32) {
        #pragma unroll
        for (int r = 0; r < 2; ++r) {
            int chunk = wave * 2 + r;
            int row = chunk * 16 + ldrow;
            __builtin_amdgcn_global_load_lds(
                (const AS1 unsigned int*)(A + (size_t)(m0 + row) * Kdim + k0 + ldcol),
                (AS3 unsigned int*)(Asm + chunk * 512 + lane * 8), 16, 0, 0);
            __builtin_amdgcn_global_load_lds(
                (const AS1 unsigned int*)(Bt + (size_t)(n0 + row) * Kdim + k0 + ldcol),
                (AS3 unsigned int*)(Bsm + chunk * 512 + lane * 8), 16, 0, 0);
        }
        __syncthreads();
        bf16x8 af[4], bf[4];
        #pragma unroll
        for (int m = 0; m < 4; ++m) af[m] = *(const bf16x8*)&Asm[(wr * 64 + m * 16 + frow) * 32 + fch * 8];
        #pragma unroll
        for (int n = 0; n < 4; ++n) bf[n] = *(const bf16x8*)&Bsm[(wc * 64 + n * 16 + frow) * 32 + fch * 8];
        #pragma unroll
        for (int m = 0; m < 4; ++m)
            #pragma unroll
            for (int n = 0; n < 4; ++n)
                acc[m][n] = __builtin_amdgcn_mfma_f32_16x16x32_bf16(af[m], bf[n], acc[m][n], 0, 0, 0);
        __syncthreads();
    }
    #pragma unroll
    for (int m = 0; m < 4; ++m) {
        int row = m0 + wr * 64 + m * 16 + fch * 4;
        #pragma unroll
        for (int n = 0; n < 4; ++n) {
            int col = n0 + wc * 64 + n * 16 + frow;
            #pragma unroll
            for (int j = 0; j < 4; ++j)
                C[(size_t)(row + j) * Ndim + col] = acc[m][n][j];
        }
    }
}

// ---------------------------------------------------------------- 256x256 8-phase GEMM (T1+T2+T3+T4+T5)
// C(M,N) = A(M,K) * Bt(N,K)^T. 512 thr = 8 waves (2Mx4N), BK=64, LDS 128 KiB dbuf.
// 2 K-tiles per loop iteration (compile-time buffer parity). Swizzle: 16B slot ^= (row&7),
// applied on global SOURCE (stage) and on ds_read addr; LDS dest stays linear.
enum { E_NONE = 0, E_GATEFUSE = 1, E_SILU_BF = 2, E_RES = 3 };

// memory-op order fence (keeps glds ledger + LDS reuse safe) + raw barrier.
// NO sched_barrier(0): let the compiler schedule VALU/MFMA freely (m141 lesson).
#define BARRIER do { asm volatile("" ::: "memory"); __builtin_amdgcn_s_barrier(); } while (0)

// stage one 128x64 half-tile (16 KiB): 2 x global_load_lds(16B) per thread
#define STAGE(src, grow0, tau_, ldsShortBase) do { \
    int _i = tid; \
    _Pragma("unroll") \
    for (int _r = 0; _r < 2; ++_r, _i += 512) { \
        int _row = _i >> 3, _slot = _i & 7; \
        const short* _gp = (src) + (size_t)((grow0) + _row) * Kdim + ((tau_) << 6) \
                           + ((_slot ^ (_row & 7)) << 3); \
        __builtin_amdgcn_global_load_lds((const AS1 unsigned int*)_gp, \
            (AS3 unsigned int*)(lds + (ldsShortBase) + _i * 8), 16, 0, 0); \
    } \
} while (0)

#define LOAD_A(Ab, mq) do { \
    af0 = *(const bf16x8*)((Ab) + (2*(mq))  *2048 + lrb + x0); \
    af1 = *(const bf16x8*)((Ab) + (2*(mq))  *2048 + lrb + x1); \
    af2 = *(const bf16x8*)((Ab) + (2*(mq)+1)*2048 + lrb + x0); \
    af3 = *(const bf16x8*)((Ab) + (2*(mq)+1)*2048 + lrb + x1); \
} while (0)

#define PHASE_MFMA(mA, mB) do { \
    _Pragma("unroll") \
    for (int n = 0; n < 4; ++n) { \
        acc[mA][n] = __builtin_amdgcn_mfma_f32_16x16x32_bf16(af0, bfrag[n][0], acc[mA][n], 0, 0, 0); \
        acc[mA][n] = __builtin_amdgcn_mfma_f32_16x16x32_bf16(af1, bfrag[n][1], acc[mA][n], 0, 0, 0); \
        acc[mB][n] = __builtin_amdgcn_mfma_f32_16x16x32_bf16(af2, bfrag[n][0], acc[mB][n], 0, 0, 0); \
        acc[mB][n] = __builtin_amdgcn_mfma_f32_16x16x32_bf16(af3, bfrag[n][1], acc[mB][n], 0, 0, 0); \
    } \
} while (0)

// one K-tile = 4 phases. Ab/Bb: this tile's LDS bases (compile-time parity).
// pB = this tile's buffer short-offset, pN = other buffer short-offset.
#define KTILE(Ab, Bb, pB, pN, tau_) do { \
    bf16x8 af0, af1, af2, af3; \
    /* phase 1: A m=0,1 + all B frags; stage A1(tau+1) */ \
    LOAD_A(Ab, 0); \
    _Pragma("unroll") \
    for (int n = 0; n < 4; ++n) { \
        bfrag[n][0] = *(const bf16x8*)((Bb) + n * 2048 + lrb + x0); \
        bfrag[n][1] = *(const bf16x8*)((Bb) + n * 2048 + lrb + x1); \
    } \
    if ((tau_) + 1 < NT) STAGE(A, m0 + 128, (tau_) + 1, (pN) + 8192); \
    BARRIER; \
    __builtin_amdgcn_s_setprio(1); \
    PHASE_MFMA(0, 1); \
    __builtin_amdgcn_s_setprio(0); \
    BARRIER; \
    /* phase 2: A m=2,3; stage B0(tau+2) */ \
    LOAD_A(Ab, 1); \
    if ((tau_) + 2 < NT) STAGE(Bt, n0, (tau_) + 2, (pB) + 16384); \
    BARRIER; \
    __builtin_amdgcn_s_setprio(1); \
    PHASE_MFMA(2, 3); \
    __builtin_amdgcn_s_setprio(0); \
    BARRIER; \
    /* phase 3: A m=4,5; stage B1(tau+2) */ \
    LOAD_A(Ab, 2); \
    if ((tau_) + 2 < NT) STAGE(Bt, n0 + 128, (tau_) + 2, (pB) + 16384 + 8192); \
    BARRIER; \
    __builtin_amdgcn_s_setprio(1); \
    PHASE_MFMA(4, 5); \
    __builtin_amdgcn_s_setprio(0); \
    BARRIER; \
    /* phase 4: A m=6,7; stage A0(tau+2) after MFMA; counted vmcnt */ \
    LOAD_A(Ab, 3); \
    BARRIER; \
    __builtin_amdgcn_s_setprio(1); \
    PHASE_MFMA(6, 7); \
    __builtin_amdgcn_s_setprio(0); \
    if ((tau_) + 2 < NT) { \
        STAGE(A, m0, (tau_) + 2, (pB)); \
        asm volatile("s_waitcnt vmcnt(6)" ::: "memory"); \
    } else { \
        asm volatile("s_waitcnt vmcnt(0)" ::: "memory"); \
    } \
    BARRIER; \
} while (0)

template <int EPI>
__global__ __launch_bounds__(512, 2) void gemm256(const short* __restrict__ A,
                                                  const short* __restrict__ Bt,
                                                  void* __restrict__ C,
                                                  int Ndim, int Kdim,
                                                  const float* __restrict__ bias,
                                                  const float* __restrict__ res,
                                                  const float* __restrict__ xin,
                                                  const float* __restrict__ outp) {
    __shared__ short lds[65536];                 // 128 KiB: 2 buf x (A 2x8192 | B 2x8192)
    const int NT = Kdim >> 6;
    const int nb = Ndim >> 8;
    int nwg = gridDim.x;
    int wg  = blockIdx.x;
    int swz = (wg & 7) * (nwg >> 3) + (wg >> 3);     // bijective: nwg % 8 == 0
    int bm = swz / nb, bn = swz % nb;
    int m0 = bm << 8, n0 = bn << 8;
    int tid = threadIdx.x, lane = tid & 63, wave = tid >> 6;
    int wr = wave >> 2, wc = wave & 3;
    int frow = lane & 15, fch = lane >> 4;

    f32x4 acc[8][4] = {};
    bf16x8 bfrag[4][2];

    // lane-constant read offsets (bytes within one 128x64 half; 16B-slot swizzle)
    int lrb = frow * 128;
    int sx  = frow & 7;
    int x0  = (fch ^ sx) << 4;
    int x1  = ((fch + 4) ^ sx) << 4;

    // compile-time-parity LDS bases
    const char* Ab0 = (const char*)lds + wr * 16384;
    const char* Bb0 = (const char*)lds + 32768 + (wc >> 1) * 16384 + (wc & 1) * 8192;
    const char* Ab1 = Ab0 + 65536;
    const char* Bb1 = Bb0 + 65536;

    // prologue: tile0 (4 halves -> buf0) + B0,B1,A0 of tile1 -> buf1
    STAGE(Bt, n0,       0, 16384);
    STAGE(Bt, n0 + 128, 0, 16384 + 8192);
    STAGE(A,  m0,       0, 0);
    STAGE(A,  m0 + 128, 0, 8192);
    if (NT > 1) {
        STAGE(Bt, n0,       1, 32768 + 16384);
        STAGE(Bt, n0 + 128, 1, 32768 + 16384 + 8192);
        STAGE(A,  m0,       1, 32768);
    }
    asm volatile("s_waitcnt vmcnt(6)" ::: "memory");
    BARRIER;

    // 2 K-tiles per iteration, static buffer parity
    for (int tau = 0; tau < NT; tau += 2) {
        KTILE(Ab0, Bb0, 0,     32768, tau);
        KTILE(Ab1, Bb1, 32768, 0,     tau + 1);
    }

    // epilogue
    #pragma unroll
    for (int m = 0; m < 8; ++m) {
        int row = m0 + wr * 128 + m * 16 + fch * 4;
        #pragma unroll
        for (int n = 0; n < 4; ++n) {
            int col = n0 + wc * 64 + n * 16 + frow;
            #pragma unroll
            for (int j = 0; j < 4; ++j) {
                float v = acc[m][n][j];
                size_t o = (size_t)(row + j) * Ndim + col;
                if (EPI == E_NONE) {
                    ((float*)C)[o] = v;
                } else if (EPI == E_GATEFUSE) {
                    float t = v + bias[col];
                    float s = 1.f / (1.f + __expf(-t));
                    ((float*)C)[o] = xin[o] + s * outp[o];
                } else if (EPI == E_SILU_BF) {
                    float t = v + bias[col];
                    ((short*)C)[o] = f2bf(t / (1.f + __expf(-t)));
                } else {  // E_RES
                    ((float*)C)[o] = v + bias[col] + res[o];
                }
            }
        }
    }
}

// ---------------------------------------------------------------- launch
extern "C" void kernel_launch(void* const* d_in, const int* in_sizes, int n_in,
                              void* d_out, int out_size, void* d_ws, size_t ws_size,
                              hipStream_t stream) {
    const float* x          = (const float*)d_in[0];
    const float* in_proj_w  = (const float*)d_in[1];
    const float* log_decay  = (const float*)d_in[2];
    const float* frequency  = (const float*)d_in[3];
    const float* coupling   = (const float*)d_in[4];
    const float* out_proj_w = (const float*)d_in[5];
    const float* gate_w     = (const float*)d_in[6];
    const float* gate_b     = (const float*)d_in[7];
    const float* n1_g       = (const float*)d_in[8];
    const float* n1_b       = (const float*)d_in[9];
    const float* n2_g       = (const float*)d_in[10];
    const float* n2_b       = (const float*)d_in[11];
    const float* mlp_w1     = (const float*)d_in[12];
    const float* mlp_b1     = (const float*)d_in[13];
    const float* mlp_w2     = (const float*)d_in[14];
    const float* mlp_b2     = (const float*)d_in[15];

    float* out_x   = (float*)d_out;
    float* out_eig = out_x + (size_t)BT * DDIM;

    char* ws = (char*)d_ws;
    short* w_inproj  = (short*)(ws + 0);
    short* w_outproj = (short*)(ws + 262144);
    short* w_gate    = (short*)(ws + 524288);
    short* w_1       = (short*)(ws + 2621440);
    short* w_2       = (short*)(ws + 11010048);
    short* xn        = (short*)(ws + 19398656);
    float* beta      = (float*)(ws + 52953088);
    short* eig_bf    = (short*)(ws + 61341696);
    short* hid       = (short*)(ws + 65536000);     // 134217728 B (after outp dead)
    float* outp      = (float*)(ws + 132644864);    // 67108864 B

    cvt_bf16_kernel<<<64,   256, 0, stream>>>(in_proj_w,  w_inproj,  131072 / 4);
    cvt_bf16_kernel<<<64,   256, 0, stream>>>(out_proj_w, w_outproj, 131072 / 4);
    cvt_bf16_kernel<<<256,  256, 0, stream>>>(gate_w,     w_gate,    1048576 / 4);
    cvt_bf16_kernel<<<1024, 256, 0, stream>>>(mlp_w1,     w_1,       4194304 / 4);
    cvt_bf16_kernel<<<1024, 256, 0, stream>>>(mlp_w2,     w_2,       4194304 / 4);

    // xn = LN1(x)
    ln_kernel<<<BT, 256, 0, stream>>>(x, n1_g, n1_b, xn);

    // beta = xn @ in_proj_w^T  (N=128, K=1024) - small kernel
    gemm_bt<<<BT / 128, 256, 0, stream>>>(xn, w_inproj, beta, 128, 1024);

    // eig conv + coupling
    eig_kernel<<<BATCH * (TLEN / EIG_TT), 256, 0, stream>>>(beta, log_decay, frequency, coupling, out_eig, eig_bf);

    // out = eig @ out_proj_w^T  (N=1024, K=128)
    gemm256<E_NONE><<<(BT / 256) * (1024 / 256), 512, 0, stream>>>(
        eig_bf, w_outproj, outp, 1024, 128, nullptr, nullptr, nullptr, nullptr);

    // x1 = x + sigmoid(xn @ gate_w^T + gate_b) * outp  -> d_out  (N=1024, K=1024)
    gemm256<E_GATEFUSE><<<(BT / 256) * (1024 / 256), 512, 0, stream>>>(
        xn, w_gate, out_x, 1024, 1024, gate_b, nullptr, x, outp);

    // x2n = LN2(x1)
    ln_kernel<<<BT, 256, 0, stream>>>(out_x, n2_g, n2_b, xn);

    // hid = silu(x2n @ mlp_w1^T + b1) bf16  (N=4096, K=1024)
    gemm256<E_SILU_BF><<<(BT / 256) * (4096 / 256), 512, 0, stream>>>(
        xn, w_1, hid, 4096, 1024, mlp_b1, nullptr, nullptr, nullptr);

    // x = x1 + hid @ mlp_w2^T + b2  (N=1024, K=4096), in-place RMW on d_out
    gemm256<E_RES><<<(BT / 256) * (1024 / 256), 512, 0, stream>>>(
        hid, w_2, out_x, 1024, 4096, mlp_b2, out_x, nullptr, nullptr);
}

// Round 6
// 617.725 us; speedup vs baseline: 1.3852x; 1.0198x over previous
//
#include <hip/hip_runtime.h>
#include <hip/hip_bf16.h>
#include <math.h>

// Problem constants (fixed by setup_inputs)
#define BATCH 4
#define TLEN  4096
#define DDIM  1024
#define BT    16384     // BATCH*TLEN

typedef __attribute__((ext_vector_type(8))) __bf16 bf16x8;
typedef __attribute__((ext_vector_type(4))) float  f32x4;

#define AS1 __attribute__((address_space(1)))
#define AS3 __attribute__((address_space(3)))

__device__ __forceinline__ short f2bf(float f) {
    union { float f; unsigned int i; } u; u.f = f;
    unsigned int r = u.i + 0x7FFF + ((u.i >> 16) & 1);  // round-to-nearest-even
    return (short)(r >> 16);
}

// ---------------------------------------------------------------- converts
__global__ void cvt_bf16_kernel(const float* __restrict__ in, short* __restrict__ out, int n4) {
    int i = blockIdx.x * blockDim.x + threadIdx.x;
    int stride = gridDim.x * blockDim.x;
    for (; i < n4; i += stride) {
        float4 v = ((const float4*)in)[i];
        short4 o = make_short4(f2bf(v.x), f2bf(v.y), f2bf(v.z), f2bf(v.w));
        ((short4*)out)[i] = o;
    }
}

// ---------------------------------------------------------------- layernorm -> bf16
__global__ __launch_bounds__(256) void ln_kernel(const float* __restrict__ x,
                                                 const float* __restrict__ g,
                                                 const float* __restrict__ b,
                                                 short* __restrict__ out) {
    __shared__ float red[8];
    __shared__ float mv[2];
    int row = blockIdx.x, tid = threadIdx.x;
    const float* xr = x + (size_t)row * DDIM;
    float4 v = *(const float4*)&xr[tid * 4];
    float s  = v.x + v.y + v.z + v.w;
    float s2 = v.x*v.x + v.y*v.y + v.z*v.z + v.w*v.w;
    for (int o = 32; o; o >>= 1) { s += __shfl_down(s, o); s2 += __shfl_down(s2, o); }
    int wave = tid >> 6, lane = tid & 63;
    if (lane == 0) { red[wave] = s; red[4 + wave] = s2; }
    __syncthreads();
    if (tid == 0) {
        float ts  = red[0] + red[1] + red[2] + red[3];
        float ts2 = red[4] + red[5] + red[6] + red[7];
        float m = ts * (1.f / DDIM);
        float var = ts2 * (1.f / DDIM) - m * m;
        mv[0] = m; mv[1] = rsqrtf(var + 1e-5f);
    }
    __syncthreads();
    float m = mv[0], r = mv[1];
    const float* vv = (const float*)&v;
    short o4[4];
    #pragma unroll
    for (int j = 0; j < 4; ++j) {
        int c = tid * 4 + j;
        o4[j] = f2bf((vv[j] - m) * r * g[c] + b[c]);
    }
    *(short4*)&out[(size_t)row * DDIM + tid * 4] = make_short4(o4[0], o4[1], o4[2], o4[3]);
}

// ---------------------------------------------------------------- eig: 64-tap causal complex conv + coupling
#define EIG_TT 16
#define WIN 64
__global__ __launch_bounds__(256) void eig_kernel(const float* __restrict__ beta,
                                                  const float* __restrict__ log_decay,
                                                  const float* __restrict__ freq,
                                                  const float* __restrict__ coupling,
                                                  float* __restrict__ eig_f32,
                                                  short* __restrict__ eig_bf) {
    __shared__ float bsm[EIG_TT + WIN][128];
    __shared__ float csm[EIG_TT][128];
    __shared__ float psm[4][16][16];
    int tpb = TLEN / EIG_TT;
    int b   = blockIdx.x / tpb;
    int t0  = (blockIdx.x % tpb) * EIG_TT;
    int tid = threadIdx.x;

    for (int idx = tid; idx < (EIG_TT + WIN) * 32; idx += 256) {
        int r = idx >> 5, c4 = idx & 31;
        int t = t0 - WIN + r;
        float4 val = make_float4(0.f, 0.f, 0.f, 0.f);
        if (t >= 0) val = *(const float4*)&beta[((size_t)(b * TLEN + t)) * 128 + c4 * 4];
        *(float4*)&bsm[r][c4 * 4] = val;
    }
    for (int i = tid; i < 1024; i += 256) ((float*)psm)[i] = coupling[i];
    __syncthreads();

    int k = tid & 63;
    float mag = 1.f / (1.f + __expf(-log_decay[k]));
    float th  = freq[k];
    float lr = mag * cosf(th), li = mag * sinf(th);
    #pragma unroll
    for (int p = 0; p < 4; ++p) {
        int tl = (tid >> 6) + p * 4;
        float ar = 0.f, ai = 0.f;
        for (int s = WIN - 1; s >= 0; --s) {
            float br_ = bsm[tl + WIN - s][k];
            float bi_ = bsm[tl + WIN - s][64 + k];
            float nr = lr * ar - li * ai + br_;
            float ni = lr * ai + li * ar + bi_;
            ar = nr; ai = ni;
        }
        csm[tl][k] = ar; csm[tl][64 + k] = ai;
    }
    __syncthreads();

    #pragma unroll
    for (int p = 0; p < 8; ++p) {
        int idx = tid + p * 256;
        int c = idx & 127, tl = idx >> 7;
        int im = c >> 6, hj = c & 63, h = hj >> 4, j = hj & 15;
        float acc = 0.f;
        #pragma unroll
        for (int kk = 0; kk < 16; ++kk) acc += psm[h][j][kk] * csm[tl][im * 64 + h * 16 + kk];
        size_t o = ((size_t)(b * TLEN + t0 + tl)) * 128 + c;
        eig_f32[o] = acc;
        eig_bf[o]  = f2bf(acc);
    }
}

// ---------------------------------------------------------------- small 128x128 GEMM (beta only, N=128)
__global__ __launch_bounds__(256) void gemm_bt(const short* __restrict__ A,
                                               const short* __restrict__ Bt,
                                               float* __restrict__ C,
                                               int Ndim, int Kdim) {
    __shared__ short Asm[128 * 32];
    __shared__ short Bsm[128 * 32];
    int nb = Ndim >> 7;
    int bm = blockIdx.x / nb, bn = blockIdx.x % nb;
    int m0 = bm << 7, n0 = bn << 7;
    int tid = threadIdx.x, lane = tid & 63, wave = tid >> 6;
    int wr = wave >> 1, wc = wave & 1;
    f32x4 acc[4][4] = {};
    int ldrow = lane >> 2;
    int ldcol = (lane & 3) * 8;
    int frow = lane & 15, fch = lane >> 4;

    for (int k0 = 0; k0 < Kdim; k0 += 32) {
        #pragma unroll
        for (int r = 0; r < 2; ++r) {
            int chunk = wave * 2 + r;
            int row = chunk * 16 + ldrow;
            __builtin_amdgcn_global_load_lds(
                (const AS1 unsigned int*)(A + (size_t)(m0 + row) * Kdim + k0 + ldcol),
                (AS3 unsigned int*)(Asm + chunk * 512 + lane * 8), 16, 0, 0);
            __builtin_amdgcn_global_load_lds(
                (const AS1 unsigned int*)(Bt + (size_t)(n0 + row) * Kdim + k0 + ldcol),
                (AS3 unsigned int*)(Bsm + chunk * 512 + lane * 8), 16, 0, 0);
        }
        __syncthreads();
        bf16x8 af[4], bf[4];
        #pragma unroll
        for (int m = 0; m < 4; ++m) af[m] = *(const bf16x8*)&Asm[(wr * 64 + m * 16 + frow) * 32 + fch * 8];
        #pragma unroll
        for (int n = 0; n < 4; ++n) bf[n] = *(const bf16x8*)&Bsm[(wc * 64 + n * 16 + frow) * 32 + fch * 8];
        #pragma unroll
        for (int m = 0; m < 4; ++m)
            #pragma unroll
            for (int n = 0; n < 4; ++n)
                acc[m][n] = __builtin_amdgcn_mfma_f32_16x16x32_bf16(af[m], bf[n], acc[m][n], 0, 0, 0);
        __syncthreads();
    }
    #pragma unroll
    for (int m = 0; m < 4; ++m) {
        int row = m0 + wr * 64 + m * 16 + fch * 4;
        #pragma unroll
        for (int n = 0; n < 4; ++n) {
            int col = n0 + wc * 64 + n * 16 + frow;
            #pragma unroll
            for (int j = 0; j < 4; ++j)
                C[(size_t)(row + j) * Ndim + col] = acc[m][n][j];
        }
    }
}

// ---------------------------------------------------------------- 256x256 pipelined GEMM
// C(M,N) = A(M,K) * Bt(N,K)^T. 512 thr = 8 waves (2Mx4N), BK=64, LDS 128 KiB dbuf.
// Single-barrier phases: each window = {issue next-quadrant ds_reads || stage || MFMA(prev frags)}.
// A-frag reads pipelined one phase ahead; lgkmcnt(0) at ph3 end guards the ph4 A0 overwrite.
// Swizzle: 16B slot ^= (row&7), applied on global SOURCE (stage) and on ds_read addr.
enum { E_NONE = 0, E_GATEFUSE = 1, E_SILU_BF = 2, E_RES = 3 };

#define BARRIER do { asm volatile("" ::: "memory"); __builtin_amdgcn_s_barrier(); } while (0)

// stage one 128x64 half-tile (16 KiB): 2 x global_load_lds(16B) per thread
#define STAGE(src, grow0, tau_, ldsShortBase) do { \
    int _i = tid; \
    _Pragma("unroll") \
    for (int _r = 0; _r < 2; ++_r, _i += 512) { \
        int _row = _i >> 3, _slot = _i & 7; \
        const short* _gp = (src) + (size_t)((grow0) + _row) * Kdim + ((tau_) << 6) \
                           + ((_slot ^ (_row & 7)) << 3); \
        __builtin_amdgcn_global_load_lds((const AS1 unsigned int*)_gp, \
            (AS3 unsigned int*)(lds + (ldsShortBase) + _i * 8), 16, 0, 0); \
    } \
} while (0)

// read one A-quadrant's 4 fragments (rows 2mq,2mq+1 x k-halves x0,x1)
#define RD_AF(F, Ab, mq) do { \
    F[0] = *(const bf16x8*)((Ab) + (2*(mq))  *2048 + lrb + x0); \
    F[1] = *(const bf16x8*)((Ab) + (2*(mq))  *2048 + lrb + x1); \
    F[2] = *(const bf16x8*)((Ab) + (2*(mq)+1)*2048 + lrb + x0); \
    F[3] = *(const bf16x8*)((Ab) + (2*(mq)+1)*2048 + lrb + x1); \
} while (0)

#define MFMA_Q(mA, mB, F) do { \
    __builtin_amdgcn_s_setprio(1); \
    _Pragma("unroll") \
    for (int n = 0; n < 4; ++n) { \
        acc[mA][n] = __builtin_amdgcn_mfma_f32_16x16x32_bf16(F[0], bfrag[n][0], acc[mA][n], 0, 0, 0); \
        acc[mA][n] = __builtin_amdgcn_mfma_f32_16x16x32_bf16(F[1], bfrag[n][1], acc[mA][n], 0, 0, 0); \
        acc[mB][n] = __builtin_amdgcn_mfma_f32_16x16x32_bf16(F[2], bfrag[n][0], acc[mB][n], 0, 0, 0); \
        acc[mB][n] = __builtin_amdgcn_mfma_f32_16x16x32_bf16(F[3], bfrag[n][1], acc[mB][n], 0, 0, 0); \
    } \
    __builtin_amdgcn_s_setprio(0); \
} while (0)

// one K-tile = 4 single-barrier windows; A-frags pipelined one window ahead.
#define KTILE(Ab, Bb, pB, pN, tau_) do { \
    bf16x8 afA[4], afB[4]; \
    /* ph1: read B(8)+afA(q0)+afB(q1); stage A1(tau+1); MFMA q0 */ \
    RD_AF(afA, Ab, 0); \
    _Pragma("unroll") \
    for (int n = 0; n < 4; ++n) { \
        bfrag[n][0] = *(const bf16x8*)((Bb) + n * 2048 + lrb + x0); \
        bfrag[n][1] = *(const bf16x8*)((Bb) + n * 2048 + lrb + x1); \
    } \
    RD_AF(afB, Ab, 1); \
    if ((tau_) + 1 < NT) STAGE(A, m0 + 128, (tau_) + 1, (pN) + 8192); \
    MFMA_Q(0, 1, afA); \
    BARRIER; \
    /* ph2: read afA(q2); stage B0(tau+2); MFMA q1 */ \
    RD_AF(afA, Ab, 2); \
    if ((tau_) + 2 < NT) STAGE(Bt, n0, (tau_) + 2, (pB) + 16384); \
    MFMA_Q(2, 3, afB); \
    BARRIER; \
    /* ph3: read afB(q3); stage B1(tau+2); MFMA q2; drain lgkm before ph4's A0 overwrite */ \
    RD_AF(afB, Ab, 3); \
    if ((tau_) + 2 < NT) STAGE(Bt, n0 + 128, (tau_) + 2, (pB) + 16384 + 8192); \
    MFMA_Q(4, 5, afA); \
    asm volatile("s_waitcnt lgkmcnt(0)" ::: "memory"); \
    BARRIER; \
    /* ph4: stage A0(tau+2); MFMA q3; counted vmcnt */ \
    if ((tau_) + 2 < NT) { \
        STAGE(A, m0, (tau_) + 2, (pB)); \
        MFMA_Q(6, 7, afB); \
        asm volatile("s_waitcnt vmcnt(6)" ::: "memory"); \
    } else { \
        MFMA_Q(6, 7, afB); \
        asm volatile("s_waitcnt vmcnt(0)" ::: "memory"); \
    } \
    BARRIER; \
} while (0)

template <int EPI>
__global__ __launch_bounds__(512, 2) void gemm256(const short* __restrict__ A,
                                                  const short* __restrict__ Bt,
                                                  void* __restrict__ C,
                                                  int Ndim, int Kdim,
                                                  const float* __restrict__ bias,
                                                  const float* __restrict__ res,
                                                  const float* __restrict__ xin,
                                                  const float* __restrict__ outp) {
    __shared__ short lds[65536];                 // 128 KiB: 2 buf x (A 2x8192 | B 2x8192)
    const int NT = Kdim >> 6;
    const int nb = Ndim >> 8;
    int nwg = gridDim.x;
    int wg  = blockIdx.x;
    int swz = (wg & 7) * (nwg >> 3) + (wg >> 3);     // bijective: nwg % 8 == 0
    int bm = swz / nb, bn = swz % nb;
    int m0 = bm << 8, n0 = bn << 8;
    int tid = threadIdx.x, lane = tid & 63, wave = tid >> 6;
    int wr = wave >> 2, wc = wave & 3;
    int frow = lane & 15, fch = lane >> 4;

    f32x4 acc[8][4] = {};
    bf16x8 bfrag[4][2];

    // lane-constant read offsets (bytes within one 128x64 half; 16B-slot swizzle)
    int lrb = frow * 128;
    int sx  = frow & 7;
    int x0  = (fch ^ sx) << 4;
    int x1  = ((fch + 4) ^ sx) << 4;

    // compile-time-parity LDS bases
    const char* Ab0 = (const char*)lds + wr * 16384;
    const char* Bb0 = (const char*)lds + 32768 + (wc >> 1) * 16384 + (wc & 1) * 8192;
    const char* Ab1 = Ab0 + 65536;
    const char* Bb1 = Bb0 + 65536;

    // prologue: tile0 (4 halves -> buf0) + B0,B1,A0 of tile1 -> buf1
    STAGE(Bt, n0,       0, 16384);
    STAGE(Bt, n0 + 128, 0, 16384 + 8192);
    STAGE(A,  m0,       0, 0);
    STAGE(A,  m0 + 128, 0, 8192);
    if (NT > 1) {
        STAGE(Bt, n0,       1, 32768 + 16384);
        STAGE(Bt, n0 + 128, 1, 32768 + 16384 + 8192);
        STAGE(A,  m0,       1, 32768);
    }
    asm volatile("s_waitcnt vmcnt(6)" ::: "memory");
    BARRIER;

    // 2 K-tiles per iteration, static buffer parity
    for (int tau = 0; tau < NT; tau += 2) {
        KTILE(Ab0, Bb0, 0,     32768, tau);
        KTILE(Ab1, Bb1, 32768, 0,     tau + 1);
    }

    // epilogue
    #pragma unroll
    for (int m = 0; m < 8; ++m) {
        int row = m0 + wr * 128 + m * 16 + fch * 4;
        #pragma unroll
        for (int n = 0; n < 4; ++n) {
            int col = n0 + wc * 64 + n * 16 + frow;
            #pragma unroll
            for (int j = 0; j < 4; ++j) {
                float v = acc[m][n][j];
                size_t o = (size_t)(row + j) * Ndim + col;
                if (EPI == E_NONE) {
                    ((float*)C)[o] = v;
                } else if (EPI == E_GATEFUSE) {
                    float t = v + bias[col];
                    float s = 1.f / (1.f + __expf(-t));
                    ((float*)C)[o] = xin[o] + s * outp[o];
                } else if (EPI == E_SILU_BF) {
                    float t = v + bias[col];
                    ((short*)C)[o] = f2bf(t / (1.f + __expf(-t)));
                } else {  // E_RES
                    ((float*)C)[o] = v + bias[col] + res[o];
                }
            }
        }
    }
}

// ---------------------------------------------------------------- launch
extern "C" void kernel_launch(void* const* d_in, const int* in_sizes, int n_in,
                              void* d_out, int out_size, void* d_ws, size_t ws_size,
                              hipStream_t stream) {
    const float* x          = (const float*)d_in[0];
    const float* in_proj_w  = (const float*)d_in[1];
    const float* log_decay  = (const float*)d_in[2];
    const float* frequency  = (const float*)d_in[3];
    const float* coupling   = (const float*)d_in[4];
    const float* out_proj_w = (const float*)d_in[5];
    const float* gate_w     = (const float*)d_in[6];
    const float* gate_b     = (const float*)d_in[7];
    const float* n1_g       = (const float*)d_in[8];
    const float* n1_b       = (const float*)d_in[9];
    const float* n2_g       = (const float*)d_in[10];
    const float* n2_b       = (const float*)d_in[11];
    const float* mlp_w1     = (const float*)d_in[12];
    const float* mlp_b1     = (const float*)d_in[13];
    const float* mlp_w2     = (const float*)d_in[14];
    const float* mlp_b2     = (const float*)d_in[15];

    float* out_x   = (float*)d_out;
    float* out_eig = out_x + (size_t)BT * DDIM;

    char* ws = (char*)d_ws;
    short* w_inproj  = (short*)(ws + 0);
    short* w_outproj = (short*)(ws + 262144);
    short* w_gate    = (short*)(ws + 524288);
    short* w_1       = (short*)(ws + 2621440);
    short* w_2       = (short*)(ws + 11010048);
    short* xn        = (short*)(ws + 19398656);
    float* beta      = (float*)(ws + 52953088);
    short* eig_bf    = (short*)(ws + 61341696);
    short* hid       = (short*)(ws + 65536000);     // 134217728 B (after outp dead)
    float* outp      = (float*)(ws + 132644864);    // 67108864 B

    cvt_bf16_kernel<<<64,   256, 0, stream>>>(in_proj_w,  w_inproj,  131072 / 4);
    cvt_bf16_kernel<<<64,   256, 0, stream>>>(out_proj_w, w_outproj, 131072 / 4);
    cvt_bf16_kernel<<<256,  256, 0, stream>>>(gate_w,     w_gate,    1048576 / 4);
    cvt_bf16_kernel<<<1024, 256, 0, stream>>>(mlp_w1,     w_1,       4194304 / 4);
    cvt_bf16_kernel<<<1024, 256, 0, stream>>>(mlp_w2,     w_2,       4194304 / 4);

    // xn = LN1(x)
    ln_kernel<<<BT, 256, 0, stream>>>(x, n1_g, n1_b, xn);

    // beta = xn @ in_proj_w^T  (N=128, K=1024) - small kernel
    gemm_bt<<<BT / 128, 256, 0, stream>>>(xn, w_inproj, beta, 128, 1024);

    // eig conv + coupling
    eig_kernel<<<BATCH * (TLEN / EIG_TT), 256, 0, stream>>>(beta, log_decay, frequency, coupling, out_eig, eig_bf);

    // out = eig @ out_proj_w^T  (N=1024, K=128)
    gemm256<E_NONE><<<(BT / 256) * (1024 / 256), 512, 0, stream>>>(
        eig_bf, w_outproj, outp, 1024, 128, nullptr, nullptr, nullptr, nullptr);

    // x1 = x + sigmoid(xn @ gate_w^T + gate_b) * outp  -> d_out  (N=1024, K=1024)
    gemm256<E_GATEFUSE><<<(BT / 256) * (1024 / 256), 512, 0, stream>>>(
        xn, w_gate, out_x, 1024, 1024, gate_b, nullptr, x, outp);

    // x2n = LN2(x1)
    ln_kernel<<<BT, 256, 0, stream>>>(out_x, n2_g, n2_b, xn);

    // hid = silu(x2n @ mlp_w1^T + b1) bf16  (N=4096, K=1024)
    gemm256<E_SILU_BF><<<(BT / 256) * (4096 / 256), 512, 0, stream>>>(
        xn, w_1, hid, 4096, 1024, mlp_b1, nullptr, nullptr, nullptr);

    // x = x1 + hid @ mlp_w2^T + b2  (N=1024, K=4096), in-place RMW on d_out
    gemm256<E_RES><<<(BT / 256) * (1024 / 256), 512, 0, stream>>>(
        hid, w_2, out_x, 1024, 4096, mlp_b2, out_x, nullptr, nullptr);
}